// Round 9
// baseline (43.467 us; speedup 1.0000x reference)
//
#include <hip/hip_runtime.h>

// GatedBlock: B=16, C=128, T=64, F=128, S=62, dilation=2, fp32 in/out.
// out[b,c,s,f] = (tanh(x0*wt0+x1*wt1+bt) * sigmoid(x0*ws0+x1*ws1+bs)
//                 + sum_t x[b,c,t,f]*w_res[s,t] + b_res[s]) * w_out[c] + b_out[c]
//
// Round 9 = round 7 (27.6us, passing) with a low-pressure post-barrier phase:
//  - ct-split: per column-tile only acc[4] live; A-frags re-read from LDS per
//    (rt,kt) (transient regs; ds_reads don't build giant live ranges the way
//    hoisted global loads did in round 8's spill disaster).
//  - #pragma unroll 1 on ct forbids cross-ct hoisting.
//  - __launch_bounds__(256,6): cap ~84 VGPR (> natural ~55, so NO spills,
//    unlike round 8's (256,8)->32VGPR+scratch); LDS 26624 -> 6 blocks/CU,
//    aligned with floor(512/84)=6 waves/SIMD.
//  - single dispatch; numerics bit-identical to round 7 (absmax 0.0625).

typedef __attribute__((ext_vector_type(8)))  short short8;
typedef __attribute__((ext_vector_type(4)))  float f32x4;
typedef __attribute__((ext_vector_type(4)))  int   i32x4;
typedef __attribute__((ext_vector_type(2)))  int   i32x2;

constexpr int Bc = 16, Cc = 128, Tc = 64, Fc = 128, Sc = 62, DIL = 2;
constexpr int LDSTW    = 72;                  // bf16 per xT f-row; 144B row = 36
                                              // dwords -> banks rotate per col
constexpr int XT_BYTES = Fc * LDSTW * 2;      // 18432
constexpr int A_BYTES  = 8 * 64 * 16;         // 8192
constexpr int LDS_TOT  = XT_BYTES + A_BYTES;  // 26624

__device__ inline unsigned cvt_pk_bf16(float lo, float hi) {
    unsigned r;
    asm("v_cvt_pk_bf16_f32 %0, %1, %2" : "=v"(r) : "v"(lo), "v"(hi));
    return r;   // low16 = bf16(lo), high16 = bf16(hi), RNE
}

__device__ inline float bf16_lo(int u) { return __uint_as_float(((unsigned)u) << 16); }
__device__ inline float bf16_hi(int u) { return __uint_as_float(((unsigned)u) & 0xFFFF0000u); }

__global__ __launch_bounds__(256, 6)
void gated_mfma_kernel(const float* __restrict__ x,
                       const float* __restrict__ w_tanh,
                       const float* __restrict__ b_tanh,
                       const float* __restrict__ w_sig,
                       const float* __restrict__ b_sig,
                       const float* __restrict__ w_out,
                       const float* __restrict__ b_out,
                       const float* __restrict__ w_res,
                       const float* __restrict__ b_res,
                       float* __restrict__ out)
{
    __shared__ i32x4 smem[LDS_TOT / 16];
    char* lds_x = (char*)smem;                 // xT: [0, 18432)
    char* lds_a = (char*)smem + XT_BYTES;      // A-frags: [18432, 26624)

    const int bc   = blockIdx.x;               // (b,c) pair
    const int c    = bc & (Cc - 1);
    const int tid  = threadIdx.x;
    const int lane = tid & 63;
    const int w    = tid >> 6;                 // wave 0..3 -> col-tiles 2w,2w+1
    const int g    = lane >> 4;                // lane group 0..3
    const int r16  = lane & 15;

    const float wt0 = w_tanh[2 * c + 0], wt1 = w_tanh[2 * c + 1], bt = b_tanh[c];
    const float ws0 = w_sig[2 * c + 0],  ws1 = w_sig[2 * c + 1],  bs = b_sig[c];
    const float wo  = w_out[c],          bo  = b_out[c];

    // ---- stage x: thread (fq,tg) loads 8t x 4f block, coalesced dwordx4 ----
    const int fq = tid & 31;                   // f = 4*fq .. 4*fq+3
    const int tg = tid >> 5;                   // t = 8*tg .. 8*tg+7
    const float* xp = x + (size_t)bc * (Tc * Fc);
    f32x4 v[8];
#pragma unroll
    for (int u = 0; u < 8; ++u)
        v[u] = *(const f32x4*)(xp + (8 * tg + u) * Fc + 4 * fq);

    // ---- stage w_res as bf16 A-fragments (explicit slot; verified r7) ----
    // unit u=(row=u>>3, k8=u&7) holds w_res[row][8k8..8k8+7];
    // slot = (2*(row>>4) + (k8>>2))*64 + (k8&3)*16 + (row&15); read is linear.
#pragma unroll
    for (int i = 0; i < 2; ++i) {
        const int u   = tid + 256 * i;         // 0..511
        const int row = u >> 3;
        const int k8  = u & 7;
        f32x4 a0 = f32x4{0.f, 0.f, 0.f, 0.f};
        f32x4 a1 = f32x4{0.f, 0.f, 0.f, 0.f};
        if (row < Sc) {
            const float* wr = w_res + row * Tc + 8 * k8;
            a0 = *(const f32x4*)(wr);
            a1 = *(const f32x4*)(wr + 4);
        }
        const unsigned p0 = cvt_pk_bf16(a0.x, a0.y);
        const unsigned p1 = cvt_pk_bf16(a0.z, a0.w);
        const unsigned p2 = cvt_pk_bf16(a1.x, a1.y);
        const unsigned p3 = cvt_pk_bf16(a1.z, a1.w);
        const int slot = ((row >> 4) * 2 + (k8 >> 2)) * 64 + (k8 & 3) * 16 + (row & 15);
        *(i32x4*)(lds_a + slot * 16) = i32x4{(int)p0, (int)p1, (int)p2, (int)p3};
    }

    // ---- xT writes: 4 x ds_write_b128, swizzle t~ = t ^ 8*((f>>2)&3) ----
    const int tsw = 8 * (tg ^ (fq & 3));
#pragma unroll
    for (int fj = 0; fj < 4; ++fj) {
        const unsigned p0 = cvt_pk_bf16(v[0][fj], v[1][fj]);
        const unsigned p1 = cvt_pk_bf16(v[2][fj], v[3][fj]);
        const unsigned p2 = cvt_pk_bf16(v[4][fj], v[5][fj]);
        const unsigned p3 = cvt_pk_bf16(v[6][fj], v[7][fj]);
        *(i32x4*)(lds_x + ((4 * fq + fj) * LDSTW + tsw) * 2) =
            i32x4{(int)p0, (int)p1, (int)p2, (int)p3};
    }

    // ---- b_res values for acc init (clamped tail; rows>=62 masked later) ----
    f32x4 bv[4];
#pragma unroll
    for (int rt = 0; rt < 4; ++rt)
#pragma unroll
        for (int j = 0; j < 4; ++j) {
            const int idx = 16 * rt + 4 * g + j;
            bv[rt][j] = b_res[idx < Sc ? idx : Sc - 1];
        }

    __syncthreads();

    const int col0 = 32 * w + r16;
    const int swz8 = 8 * (g ^ (r16 >> 2));     // B-frag t-swizzle bits
    const int sw8  = 8 * (r16 >> 2);           // epilogue tap swizzle bits
    float* op = out + (size_t)bc * (Sc * Fc);

#pragma unroll 1
    for (int ct = 0; ct < 2; ++ct) {
        const int col = col0 + 16 * ct;

        // acc init = b_res[row] (C-operand of MFMA)
        f32x4 acc[4];
#pragma unroll
        for (int rt = 0; rt < 4; ++rt) acc[rt] = bv[rt];

        // MFMA: B one ds_read_b128 per kt; A re-read from LDS per (rt,kt)
#pragma unroll
        for (int kt = 0; kt < 2; ++kt) {
            const short8 Bf = *(const short8*)(lds_x +
                                (col * LDSTW + 32 * kt + swz8) * 2);
#pragma unroll
            for (int rt = 0; rt < 4; ++rt) {
                const short8 Af = *(const short8*)(lds_a +
                                    ((rt * 2 + kt) * 64 + lane) * 16);
                acc[rt] = __builtin_amdgcn_mfma_f32_16x16x32_bf16(Af, Bf, acc[rt], 0, 0, 0);
            }
        }

        // epilogue for this ct: taps via 2 x ds_read_b64 bf16 per rt
#pragma unroll
        for (int rt = 0; rt < 4; ++rt) {
            const int r0 = 16 * rt + 4 * g;
            const i32x2 d1 = *(const i32x2*)(lds_x + (col * LDSTW + (r0 ^ sw8)) * 2);
            const i32x2 d2 = *(const i32x2*)(lds_x + (col * LDSTW + ((r0 + 4) ^ sw8)) * 2);
            const float t0 = bf16_lo(d1.x);    // x[r0]
            const float t1 = bf16_hi(d1.x);    // x[r0+1]
            const float t2 = bf16_lo(d1.y);    // x[r0+2]
            const float t3 = bf16_hi(d1.y);    // x[r0+3]
            const float t4 = bf16_lo(d2.x);    // x[r0+4] (garbage if >=64: masked)
            const float t5 = bf16_hi(d2.x);    // x[r0+5]

#define GATE_OUT(reg, xa, xb)                                                     \
            if (r0 + (reg) < Sc) {                                                \
                const float xt  = fmaf((xa), wt0, fmaf((xb), wt1, bt));           \
                const float xsg = fmaf((xa), ws0, fmaf((xb), ws1, bs));           \
                const float e2  = __expf(2.0f * xt);                              \
                const float em  = __expf(-xsg);                                   \
                const float gate = (e2 - 1.0f) *                                  \
                    __builtin_amdgcn_rcpf((e2 + 1.0f) * (1.0f + em));             \
                op[(r0 + (reg)) * Fc + col] =                                     \
                    fmaf(gate + acc[rt][reg], wo, bo);                            \
            }
            GATE_OUT(0, t0, t2)
            GATE_OUT(1, t1, t3)
            GATE_OUT(2, t2, t4)
            GATE_OUT(3, t3, t5)
#undef GATE_OUT
        }
    }
}

extern "C" void kernel_launch(void* const* d_in, const int* in_sizes, int n_in,
                              void* d_out, int out_size, void* d_ws, size_t ws_size,
                              hipStream_t stream)
{
    const float* x      = (const float*)d_in[0];
    const float* w_tanh = (const float*)d_in[1];
    const float* b_tanh = (const float*)d_in[2];
    const float* w_sig  = (const float*)d_in[3];
    const float* b_sig  = (const float*)d_in[4];
    const float* w_out  = (const float*)d_in[5];
    const float* b_out  = (const float*)d_in[6];
    const float* w_res  = (const float*)d_in[7];
    const float* b_res  = (const float*)d_in[8];
    // d_in[9] = dilation (==2) -> compile-time DIL.

    float* out = (float*)d_out;

    gated_mfma_kernel<<<Bc * Cc, 256, 0, stream>>>(
        x, w_tanh, b_tanh, w_sig, b_sig, w_out, b_out, w_res, b_res, out);
}

// Round 10
// 43.310 us; speedup vs baseline: 1.0036x; 1.0036x over previous
//
#include <hip/hip_runtime.h>

// GatedBlock: B=16, C=128, T=64, F=128, S=62, dilation=2, fp32 in/out.
// out[b,c,s,f] = (tanh(x0*wt0+x1*wt1+bt) * sigmoid(x0*ws0+x1*ws1+bs)
//                 + sum_t x[b,c,t,f]*w_res[s,t] + b_res[s]) * w_out[c] + b_out[c]
//
// Round 10 = round 7 (27.6us best) with OPERAND-SWAPPED MFMA:
//   D = mfma(A=xT-frag, B=w-frag) = X^T @ W^T = (W@X)^T, f on the D-row axis.
//   Same lane->element maps as the verified r7 pair (addresses bit-identical);
//   only the port assignment and acc indexing change.
//  - stores: lane holds 4 CONSECUTIVE f at fixed s -> global_store_dwordx4
//    (16 vector stores/lane vs 64 scalar in r7).
//  - gate taps: fp32 dwordx4 from global x (L1/L2-hot tile), off the LDS pipe.
//  - acc init: per-st scalar broadcast of b_res (bv array gone); mandatory
//    live state 48 regs (< r7's 64) at the SAME launch_bounds (256,5) —
//    do NOT raise the bound (arg>=6 empirically spills: r8/r9).

typedef __attribute__((ext_vector_type(8)))  short short8;
typedef __attribute__((ext_vector_type(4)))  float f32x4;
typedef __attribute__((ext_vector_type(4)))  int   i32x4;

constexpr int Bc = 16, Cc = 128, Tc = 64, Fc = 128, Sc = 62, DIL = 2;
constexpr int LDSTW    = 72;                  // bf16 per xT f-row
constexpr int XT_BYTES = Fc * LDSTW * 2;      // 18432
constexpr int A_BYTES  = 8 * 64 * 16;         // 8192
constexpr int LDS_TOT  = XT_BYTES + A_BYTES;  // 26624

__device__ inline unsigned cvt_pk_bf16(float lo, float hi) {
    unsigned r;
    asm("v_cvt_pk_bf16_f32 %0, %1, %2" : "=v"(r) : "v"(lo), "v"(hi));
    return r;   // low16 = bf16(lo), high16 = bf16(hi), RNE
}

__global__ __launch_bounds__(256, 5)
void gated_mfma_kernel(const float* __restrict__ x,
                       const float* __restrict__ w_tanh,
                       const float* __restrict__ b_tanh,
                       const float* __restrict__ w_sig,
                       const float* __restrict__ b_sig,
                       const float* __restrict__ w_out,
                       const float* __restrict__ b_out,
                       const float* __restrict__ w_res,
                       const float* __restrict__ b_res,
                       float* __restrict__ out)
{
    __shared__ i32x4 smem[LDS_TOT / 16];
    char* lds_x = (char*)smem;                 // xT: [0, 18432)
    char* lds_a = (char*)smem + XT_BYTES;      // w-frags: [18432, 26624)

    const int bc   = blockIdx.x;               // (b,c) pair
    const int c    = bc & (Cc - 1);
    const int tid  = threadIdx.x;
    const int lane = tid & 63;
    const int w    = tid >> 6;                 // wave 0..3 -> f-tiles 2w,2w+1
    const int g    = lane >> 4;                // lane group 0..3
    const int r16  = lane & 15;

    const float wt0 = w_tanh[2 * c + 0], wt1 = w_tanh[2 * c + 1], bt = b_tanh[c];
    const float ws0 = w_sig[2 * c + 0],  ws1 = w_sig[2 * c + 1],  bs = b_sig[c];
    const float wo  = w_out[c],          bo  = b_out[c];

    // ---- stage x: thread (fq,tg) loads 8t x 4f block, coalesced dwordx4 ----
    const int fq = tid & 31;                   // f = 4*fq .. 4*fq+3
    const int tg = tid >> 5;                   // t = 8*tg .. 8*tg+7
    const float* xp = x + (size_t)bc * (Tc * Fc);
    f32x4 v[8];
#pragma unroll
    for (int u = 0; u < 8; ++u)
        v[u] = *(const f32x4*)(xp + (8 * tg + u) * Fc + 4 * fq);

    // ---- stage w_res as bf16 fragments (explicit slot; verified r7) ----
    // unit u=(row=u>>3, k8=u&7) holds w_res[row][8k8..8k8+7];
    // slot = (2*(row>>4) + (k8>>2))*64 + (k8&3)*16 + (row&15); read is linear.
    // Used as the B-operand now: lane(g,r16) of frag (st,kt) supplies
    // B[k=8g+q][j=r16] = w_res[16st+r16][32kt+8g+q] = W^T.
#pragma unroll
    for (int i = 0; i < 2; ++i) {
        const int u   = tid + 256 * i;         // 0..511
        const int row = u >> 3;
        const int k8  = u & 7;
        f32x4 a0 = f32x4{0.f, 0.f, 0.f, 0.f};
        f32x4 a1 = f32x4{0.f, 0.f, 0.f, 0.f};
        if (row < Sc) {
            const float* wr = w_res + row * Tc + 8 * k8;
            a0 = *(const f32x4*)(wr);
            a1 = *(const f32x4*)(wr + 4);
        }
        const unsigned p0 = cvt_pk_bf16(a0.x, a0.y);
        const unsigned p1 = cvt_pk_bf16(a0.z, a0.w);
        const unsigned p2 = cvt_pk_bf16(a1.x, a1.y);
        const unsigned p3 = cvt_pk_bf16(a1.z, a1.w);
        const int slot = ((row >> 4) * 2 + (k8 >> 2)) * 64 + (k8 & 3) * 16 + (row & 15);
        *(i32x4*)(lds_a + slot * 16) = i32x4{(int)p0, (int)p1, (int)p2, (int)p3};
    }

    // ---- xT writes: 4 x ds_write_b128, swizzle t~ = t ^ 8*((f>>2)&3) ----
    const int tsw = 8 * (tg ^ (fq & 3));
#pragma unroll
    for (int fj = 0; fj < 4; ++fj) {
        const unsigned p0 = cvt_pk_bf16(v[0][fj], v[1][fj]);
        const unsigned p1 = cvt_pk_bf16(v[2][fj], v[3][fj]);
        const unsigned p2 = cvt_pk_bf16(v[4][fj], v[5][fj]);
        const unsigned p3 = cvt_pk_bf16(v[6][fj], v[7][fj]);
        *(i32x4*)(lds_x + ((4 * fq + fj) * LDSTW + tsw) * 2) =
            i32x4{(int)p0, (int)p1, (int)p2, (int)p3};
    }

    // ---- b_res broadcast values for acc init (clamped; s>=62 masked) ----
    float bb[4];
#pragma unroll
    for (int st = 0; st < 4; ++st) {
        const int s = 16 * st + r16;
        bb[st] = b_res[s < Sc ? s : Sc - 1];
    }

    __syncthreads();

    // ---- A-operand: xT fragments. lane(g,r16) of (i,kt) supplies
    // A[i'=r16][k=8g+q] = X[t=32kt+8g+q][f=32w+16i+r16] = X^T.
    // Address identical to r7's B-frag read (col0 -> f-row).
    const int fr0  = 32 * w + r16;
    const int swz8 = 8 * (g ^ (r16 >> 2));
    short8 Af[2][2];
#pragma unroll
    for (int i = 0; i < 2; ++i)
#pragma unroll
        for (int kt = 0; kt < 2; ++kt)
            Af[i][kt] = *(const short8*)(lds_x +
                          ((fr0 + 16 * i) * LDSTW + 32 * kt + swz8) * 2);

    // ---- MFMA: D[f][s] per wave: 2 f-tiles x 4 s-tiles x 2 kt ----
    f32x4 acc[2][4];
#pragma unroll
    for (int i = 0; i < 2; ++i)
#pragma unroll
        for (int st = 0; st < 4; ++st)
            acc[i][st] = f32x4{bb[st], bb[st], bb[st], bb[st]};

#pragma unroll
    for (int st = 0; st < 4; ++st)
#pragma unroll
        for (int kt = 0; kt < 2; ++kt) {
            const short8 Bf = *(const short8*)(lds_a + ((st * 2 + kt) * 64 + lane) * 16);
#pragma unroll
            for (int i = 0; i < 2; ++i)
                acc[i][st] = __builtin_amdgcn_mfma_f32_16x16x32_bf16(
                    Af[i][kt], Bf, acc[i][st], 0, 0, 0);
        }

    // ---- epilogue: D row = f (4 consecutive per lane) -> dwordx4 stores;
    // taps fp32 dwordx4 from global (L1/L2-hot tile) ----
    float* op = out + (size_t)bc * (Sc * Fc);
#pragma unroll
    for (int i = 0; i < 2; ++i) {
        const int f = 32 * w + 16 * i + 4 * g;
#pragma unroll
        for (int st = 0; st < 4; ++st) {
            const int s = 16 * st + r16;
            if (s < Sc) {
                const f32x4 x0 = *(const f32x4*)(xp + s * Fc + f);
                const f32x4 x1 = *(const f32x4*)(xp + (s + DIL) * Fc + f);
                f32x4 r;
#pragma unroll
                for (int j = 0; j < 4; ++j) {
                    const float xt  = fmaf(x0[j], wt0, fmaf(x1[j], wt1, bt));
                    const float xsg = fmaf(x0[j], ws0, fmaf(x1[j], ws1, bs));
                    const float e2  = __expf(2.0f * xt);
                    const float em  = __expf(-xsg);
                    const float gate = (e2 - 1.0f) *
                        __builtin_amdgcn_rcpf((e2 + 1.0f) * (1.0f + em));
                    r[j] = fmaf(gate + acc[i][st][j], wo, bo);
                }
                *(f32x4*)(op + s * Fc + f) = r;
            }
        }
    }
}

extern "C" void kernel_launch(void* const* d_in, const int* in_sizes, int n_in,
                              void* d_out, int out_size, void* d_ws, size_t ws_size,
                              hipStream_t stream)
{
    const float* x      = (const float*)d_in[0];
    const float* w_tanh = (const float*)d_in[1];
    const float* b_tanh = (const float*)d_in[2];
    const float* w_sig  = (const float*)d_in[3];
    const float* b_sig  = (const float*)d_in[4];
    const float* w_out  = (const float*)d_in[5];
    const float* b_out  = (const float*)d_in[6];
    const float* w_res  = (const float*)d_in[7];
    const float* b_res  = (const float*)d_in[8];
    // d_in[9] = dilation (==2) -> compile-time DIL.

    float* out = (float*)d_out;

    gated_mfma_kernel<<<Bc * Cc, 256, 0, stream>>>(
        x, w_tanh, b_tanh, w_sig, b_sig, w_out, b_out, w_res, b_res, out);
}

// Round 11
// 27.548 us; speedup vs baseline: 1.5779x; 1.5721x over previous
//
#include <hip/hip_runtime.h>

// GatedBlock: B=16, C=128, T=64, F=128, S=62, dilation=2, fp32 in/out.
// out[b,c,s,f] = (tanh(x0*wt0+x1*wt1+bt) * sigmoid(x0*ws0+x1*ws1+bs)
//                 + sum_t x[b,c,t,f]*w_res[s,t] + b_res[s]) * w_out[c] + b_out[c]
//
// Round 11 = VERBATIM revert to round 7 (27.57us, the measured best).
// r8 ((256,8): VGPR crushed to 32, 50MB scratch), r9 ((256,6): 40 VGPR, 42MB
// scratch), r10 (operand swap at (256,5): 40 VGPR, 10MB scratch + L2-miss
// taps) all regressed — every structural deviation from this kernel triggers
// hipcc's spill pathology. Keeping the (256,5) + acc[4][2]+A[4][2] structure
// that is empirically clean.

typedef __attribute__((ext_vector_type(8)))  short short8;
typedef __attribute__((ext_vector_type(4)))  float f32x4;
typedef __attribute__((ext_vector_type(4)))  int   i32x4;
typedef __attribute__((ext_vector_type(2)))  int   i32x2;

constexpr int Bc = 16, Cc = 128, Tc = 64, Fc = 128, Sc = 62, DIL = 2;
constexpr int LDSTW    = 72;                  // bf16 elems per xT f-row (mult of 8)
constexpr int XT_BYTES = Fc * LDSTW * 2;      // 18432
constexpr int A_BYTES  = 8 * 64 * 16;         // 8192
constexpr int LDS_TOT  = XT_BYTES + A_BYTES;  // 26624

__device__ inline unsigned cvt_pk_bf16(float lo, float hi) {
    unsigned r;
    asm("v_cvt_pk_bf16_f32 %0, %1, %2" : "=v"(r) : "v"(lo), "v"(hi));
    return r;   // low16 = bf16(lo), high16 = bf16(hi), RNE
}

__device__ inline float bf16_lo(int u) { return __uint_as_float(((unsigned)u) << 16); }
__device__ inline float bf16_hi(int u) { return __uint_as_float(((unsigned)u) & 0xFFFF0000u); }

__global__ __launch_bounds__(256, 5)
void gated_mfma_kernel(const float* __restrict__ x,
                       const float* __restrict__ w_tanh,
                       const float* __restrict__ b_tanh,
                       const float* __restrict__ w_sig,
                       const float* __restrict__ b_sig,
                       const float* __restrict__ w_out,
                       const float* __restrict__ b_out,
                       const float* __restrict__ w_res,
                       const float* __restrict__ b_res,
                       float* __restrict__ out)
{
    __shared__ i32x4 smem[LDS_TOT / 16];
    char* lds_base = (char*)smem;              // xT: [0, 18432)
    char* lds_a    = lds_base + XT_BYTES;      // A-frags: [18432, 26624)

    const int bc   = blockIdx.x;               // (b,c) pair
    const int c    = bc & (Cc - 1);
    const int tid  = threadIdx.x;
    const int lane = tid & 63;
    const int w    = tid >> 6;                 // wave 0..3 -> col-tiles 2w,2w+1
    const int g    = lane >> 4;                // lane group 0..3
    const int r16  = lane & 15;

    const float wt0 = w_tanh[2 * c + 0], wt1 = w_tanh[2 * c + 1], bt = b_tanh[c];
    const float ws0 = w_sig[2 * c + 0],  ws1 = w_sig[2 * c + 1],  bs = b_sig[c];
    const float wo  = w_out[c],          bo  = b_out[c];

    // ---- stage x: thread (fq,tg) loads 8t x 4f block, coalesced dwordx4 ----
    const int fq = tid & 31;                   // f = 4*fq .. 4*fq+3
    const int tg = tid >> 5;                   // t = 8*tg .. 8*tg+7
    const float* xp = x + (size_t)bc * (Tc * Fc);
    f32x4 v[8];
#pragma unroll
    for (int u = 0; u < 8; ++u)
        v[u] = *(const f32x4*)(xp + (8 * tg + u) * Fc + 4 * fq);

    // ---- stage w_res as bf16 A-fragments (explicit slot, verified) ----
    // unit u=(row=u>>3, k8=u&7) holds w_res[row][8k8..8k8+7];
    // slot = (2*(row>>4) + (k8>>2))*64 + (k8&3)*16 + (row&15); read is linear.
#pragma unroll
    for (int i = 0; i < 2; ++i) {
        const int u   = tid + 256 * i;         // 0..511
        const int row = u >> 3;
        const int k8  = u & 7;
        f32x4 a0 = f32x4{0.f, 0.f, 0.f, 0.f};
        f32x4 a1 = f32x4{0.f, 0.f, 0.f, 0.f};
        if (row < Sc) {
            const float* wr = w_res + row * Tc + 8 * k8;
            a0 = *(const f32x4*)(wr);
            a1 = *(const f32x4*)(wr + 4);
        }
        const unsigned p0 = cvt_pk_bf16(a0.x, a0.y);
        const unsigned p1 = cvt_pk_bf16(a0.z, a0.w);
        const unsigned p2 = cvt_pk_bf16(a1.x, a1.y);
        const unsigned p3 = cvt_pk_bf16(a1.z, a1.w);
        const int slot = ((row >> 4) * 2 + (k8 >> 2)) * 64 + (k8 & 3) * 16 + (row & 15);
        *(i32x4*)(lds_a + slot * 16) = i32x4{(int)p0, (int)p1, (int)p2, (int)p3};
    }

    // ---- xT writes: 4 x ds_write_b128, swizzle t~ = t ^ 8*((f>>2)&3) ----
    const int tsw = 8 * (tg ^ (fq & 3));
#pragma unroll
    for (int fj = 0; fj < 4; ++fj) {
        const unsigned p0 = cvt_pk_bf16(v[0][fj], v[1][fj]);
        const unsigned p1 = cvt_pk_bf16(v[2][fj], v[3][fj]);
        const unsigned p2 = cvt_pk_bf16(v[4][fj], v[5][fj]);
        const unsigned p3 = cvt_pk_bf16(v[6][fj], v[7][fj]);
        *(i32x4*)(lds_base + ((4 * fq + fj) * LDSTW + tsw) * 2) =
            i32x4{(int)p0, (int)p1, (int)p2, (int)p3};
    }

    // ---- acc init = b_res[row] (C-operand); clamp tail (rows>=62 masked) ----
    f32x4 acc[4][2];
#pragma unroll
    for (int rt = 0; rt < 4; ++rt) {
        f32x4 bv;
#pragma unroll
        for (int j = 0; j < 4; ++j) {
            const int idx = 16 * rt + 4 * g + j;
            bv[j] = b_res[idx < Sc ? idx : Sc - 1];
        }
        acc[rt][0] = bv;
        acc[rt][1] = bv;
    }

    __syncthreads();

    // ---- A fragments from LDS (linear b128, conflict-free) ----
    short8 A[4][2];
#pragma unroll
    for (int rt = 0; rt < 4; ++rt)
#pragma unroll
        for (int kt = 0; kt < 2; ++kt)
            A[rt][kt] = *(const short8*)(lds_a + ((rt * 2 + kt) * 64 + lane) * 16);

    // ---- B frags: one b128 each; MFMA 2kt x 2ct x 4rt ----
    const int col0 = 32 * w + r16;
    const int swz8 = 8 * (g ^ (r16 >> 2));     // sw(col) = r16>>2 for all our cols
#pragma unroll
    for (int kt = 0; kt < 2; ++kt) {
        short8 Bf[2];
#pragma unroll
        for (int ct = 0; ct < 2; ++ct)
            Bf[ct] = *(const short8*)(lds_base +
                        ((col0 + 16 * ct) * LDSTW + 32 * kt + swz8) * 2);
#pragma unroll
        for (int rt = 0; rt < 4; ++rt)
#pragma unroll
            for (int ct = 0; ct < 2; ++ct)
                acc[rt][ct] = __builtin_amdgcn_mfma_f32_16x16x32_bf16(
                    A[rt][kt], Bf[ct], acc[rt][ct], 0, 0, 0);
    }

    // ---- epilogue: taps via 2 x ds_read_b64 bf16; gate; store ----
    const int sw8 = 8 * (r16 >> 2);            // swizzle bits for tap addressing
    float* op = out + (size_t)bc * (Sc * Fc);
#pragma unroll
    for (int rt = 0; rt < 4; ++rt) {
        const int r0 = 16 * rt + 4 * g;
#pragma unroll
        for (int ct = 0; ct < 2; ++ct) {
            const int col = col0 + 16 * ct;
            const i32x2 d1 = *(const i32x2*)(lds_base + (col * LDSTW + (r0 ^ sw8)) * 2);
            const i32x2 d2 = *(const i32x2*)(lds_base + (col * LDSTW + ((r0 + 4) ^ sw8)) * 2);
            const float t0 = bf16_lo(d1.x);    // x[r0]
            const float t1 = bf16_hi(d1.x);    // x[r0+1]
            const float t2 = bf16_lo(d1.y);    // x[r0+2]
            const float t3 = bf16_hi(d1.y);    // x[r0+3]
            const float t4 = bf16_lo(d2.x);    // x[r0+4] (garbage if r0+4>=64: masked)
            const float t5 = bf16_hi(d2.x);    // x[r0+5]

#define GATE_OUT(reg, xa, xb)                                                     \
            if (r0 + (reg) < Sc) {                                                \
                const float xt  = fmaf((xa), wt0, fmaf((xb), wt1, bt));           \
                const float xsg = fmaf((xa), ws0, fmaf((xb), ws1, bs));           \
                const float e2  = __expf(2.0f * xt);                              \
                const float em  = __expf(-xsg);                                   \
                const float gate = (e2 - 1.0f) *                                  \
                    __builtin_amdgcn_rcpf((e2 + 1.0f) * (1.0f + em));             \
                op[(r0 + (reg)) * Fc + col] =                                     \
                    fmaf(gate + acc[rt][ct][reg], wo, bo);                        \
            }
            GATE_OUT(0, t0, t2)
            GATE_OUT(1, t1, t3)
            GATE_OUT(2, t2, t4)
            GATE_OUT(3, t3, t5)
#undef GATE_OUT
        }
    }
}

extern "C" void kernel_launch(void* const* d_in, const int* in_sizes, int n_in,
                              void* d_out, int out_size, void* d_ws, size_t ws_size,
                              hipStream_t stream)
{
    const float* x      = (const float*)d_in[0];
    const float* w_tanh = (const float*)d_in[1];
    const float* b_tanh = (const float*)d_in[2];
    const float* w_sig  = (const float*)d_in[3];
    const float* b_sig  = (const float*)d_in[4];
    const float* w_out  = (const float*)d_in[5];
    const float* b_out  = (const float*)d_in[6];
    const float* w_res  = (const float*)d_in[7];
    const float* b_res  = (const float*)d_in[8];
    // d_in[9] = dilation (==2) -> compile-time DIL.

    float* out = (float*)d_out;

    gated_mfma_kernel<<<Bc * Cc, 256, 0, stream>>>(
        x, w_tanh, b_tanh, w_sig, b_sig, w_out, b_out, w_res, b_res, out);
}